// Round 4
// baseline (101.648 us; speedup 1.0000x reference)
//
#include <hip/hip_runtime.h>
#include <hip/hip_bf16.h>
#include <stdint.h>

// Maj3FC: out[b,c] = 2.25 * sum_g sign( sum_{k<3} sign(x[b,3g+k])*sign(w[c,3g+k]) )
// B=512, C_IN=1536, C_OUT=512, G=512 groups of 3. Exact integer math -> absmax 0.
//
// R4: attack the measured latency bound (R3: VALUBusy 17.6%, Occ 20%).
//  - 16x16 tiles -> 1024 blocks -> 4 blocks/CU -> 16 waves/CU (50% occ).
//  - explicit register prefetch in the inner loop (load i+1 while computing i)
//    to break the load-use adjacency the compiler chose at VGPR=36.
//  - 4 independent accumulator chains for ILP.
// Packing (R3): 3-bit fields, 10 groups/word, 52 words/row.

#define CIN    1536
#define B_DIM  512
#define COUT   512
#define WORDS3 52   // ceil(512 groups / 10 per word); word 51 holds 2 groups
#define WSTRIDE 54  // LDS row stride in uint2 (= 27 uint4); 108 dwords % 32 = 12

// ---------------- pack kernel ----------------
// 256 blocks x 256 threads. Blocks 0..127 pack x (4 rows each), 128..255 pack
// w. Coalesced float4 staging into LDS, then 1 thread per packed word.
__global__ __launch_bounds__(256) void pack_kernel(
    const float* __restrict__ x, const float* __restrict__ w,
    uint2* __restrict__ px, uint2* __restrict__ pw) {
  __shared__ float buf[4 * CIN];
  int bid = blockIdx.x;
  const float* src;
  uint2* dst;
  int row0;
  if (bid < 128) { src = x;  dst = px; row0 = bid * 4; }
  else           { src = w;  dst = pw; row0 = (bid - 128) * 4; }

  const float4* s4 = (const float4*)(src + (size_t)row0 * CIN);
  float4* b4 = (float4*)buf;
  #pragma unroll
  for (int i = threadIdx.x; i < 4 * CIN / 4; i += 256) b4[i] = s4[i];
  __syncthreads();

  int r  = threadIdx.x >> 6;   // 0..3 row within block
  int wd = threadIdx.x & 63;   // 0..63; only 0..51 active
  if (wd < WORDS3) {
    const float* rowp = buf + r * CIN + wd * 30;
    int nmax = CIN - wd * 30;  // 30 for wd<51, 6 for wd==51
    unsigned P = 0, N = 0;
    #pragma unroll
    for (int k = 0; k < 30; k++) {
      if (k < nmax) {
        float v = rowp[k];
        P |= (v > 0.0f ? 1u : 0u) << k;
        N |= (v < 0.0f ? 1u : 0u) << k;
      }
    }
    dst[(size_t)(row0 + r) * WORDS3 + wd] = make_uint2(P, N);
  }
}

// ---------------- main kernel ----------------
__device__ __forceinline__ void maj3w(unsigned xp, unsigned xn,
                                      unsigned wp, unsigned wn,
                                      int& gt, int& ge) {
  const unsigned M1 = 0x09249249u;  // bit0 of each 3-bit field (10 fields)
  const unsigned M4 = 0x24924924u;  // bit2 of each field
  unsigned pos = (xp & wp) | (xn & wn);   // product == +1 per element
  unsigned neg = (xp & wn) | (xn & wp);   // product == -1
  unsigned cp = (pos & M1) + ((pos >> 1) & M1) + ((pos >> 2) & M1); // [0,3]
  unsigned cn = (neg & M1) + ((neg >> 1) & M1) + ((neg >> 2) & M1);
  unsigned u = (cp | M4) - cn;  // field = cp-cn+4 in [1,7]; bit2 <=> cp>=cn
  unsigned t = u - M1;          // field = cp-cn+3 in [0,6]; bit2 <=> cp>cn
  gt += __popc(t & M4);
  ge += __popc(u & M4);
}

// 16x16 tile, 256 threads, 1 output/thread. grid = (32,32) = 1024 blocks
// -> 4 blocks/CU, 16 waves/CU. LDS = 2*16*54*8 = 13.8 KB.
__global__ __launch_bounds__(256, 4) void maj3_kernel(
    const uint2* __restrict__ px, const uint2* __restrict__ pw,
    float* __restrict__ out) {
  __shared__ __align__(16) uint2 sx[16][WSTRIDE];
  __shared__ __align__(16) uint2 sw[16][WSTRIDE];

  const int b0 = blockIdx.y * 16;
  const int c0 = blockIdx.x * 16;
  const int tid = threadIdx.x;

  // Packed rows are dense in global: block's x region = 16*26 contiguous
  // uint4, same for w. Scatter into stride-27(uint4) LDS rows.
  const uint4* gx = (const uint4*)(px + (size_t)b0 * WORDS3);
  const uint4* gw = (const uint4*)(pw + (size_t)c0 * WORDS3);
  uint4* lx = (uint4*)sx;  // row stride 27 uint4
  uint4* lw = (uint4*)sw;
  #pragma unroll
  for (int i = tid; i < 16 * 26; i += 256) {
    int r = i / 26, wd = i - r * 26;
    lx[r * 27 + wd] = gx[i];
    lw[r * 27 + wd] = gw[i];
  }
  __syncthreads();

  const int tx = tid & 15;   // c within tile
  const int ty = tid >> 4;   // b within tile

  int gt0 = 0, ge0 = 0, gt1 = 0, ge1 = 0;
  const uint4* xr = (const uint4*)&sx[ty][0];
  const uint4* wr = (const uint4*)&sw[tx][0];

  // Register double-buffer: consume (xa,wb) while (xn,wn) loads are in
  // flight. Breaks the zero-prefetch-distance schedule seen in R3 (VGPR=36).
  uint4 xa = xr[0];
  uint4 wb = wr[0];
  #pragma unroll
  for (int i = 0; i < 26; i++) {
    uint4 xn, wn;
    if (i + 1 < 26) { xn = xr[i + 1]; wn = wr[i + 1]; }
    maj3w(xa.x, xa.y, wb.x, wb.y, gt0, ge0);
    maj3w(xa.z, xa.w, wb.z, wb.w, gt1, ge1);
    xa = xn; wb = wn;
  }

  // 520 fields counted (512 real + 8 zero-padded; each pad field yields
  // gt=0, ge=1 and cancels in the formula). sum(sign) = gt + ge - 520.
  out[(size_t)(b0 + ty) * COUT + (c0 + tx)] =
      2.25f * (float)(gt0 + ge0 + gt1 + ge1 - 520);
}

extern "C" void kernel_launch(void* const* d_in, const int* in_sizes, int n_in,
                              void* d_out, int out_size, void* d_ws, size_t ws_size,
                              hipStream_t stream) {
  const float* x = (const float*)d_in[0];   // [512, 1536]
  const float* w = (const float*)d_in[1];   // [512, 1536]
  float* out = (float*)d_out;               // [512, 512]

  uint2* px = (uint2*)d_ws;                  // [512][52] (208 KB)
  uint2* pw = px + (size_t)B_DIM * WORDS3;   // [512][52]

  pack_kernel<<<256, 256, 0, stream>>>(x, w, px, pw);

  dim3 grid(COUT / 16, B_DIM / 16);
  maj3_kernel<<<grid, 256, 0, stream>>>(px, pw, out);
}

// Round 5
// 69.882 us; speedup vs baseline: 1.4546x; 1.4546x over previous
//
#include <hip/hip_runtime.h>
#include <hip/hip_bf16.h>
#include <stdint.h>

// Maj3FC: out[b,c] = 2.25 * sum_g sign( sum_{k<3} sign(x[b,3g+k])*sign(w[c,3g+k]) )
// B=512, C_IN=1536, C_OUT=512, G=512 groups of 3. Exact integer math -> absmax 0.
//
// R5: revert R4's two novelties (launch_bounds min-occ, uninit dbuf) which
// coincided with a +30us timed regression; keep the R1/R2-proven skeleton
// (16x16 tile, 1024 blocks, 4 blocks/CU, 16 waves/CU). Attack the measured
// LDS-latency stall (R3 isolated: VALUBusy 17.6%) with:
//  - half x-row resident in registers: 13 independent ds_read_b128 issued
//    back-to-back (deep lgkm pipelining, no load-use adjacency)
//  - rotating 2-deep w prefetch (all loads valid, no uninit registers)
// Packing (R3): 3-bit fields, 10 groups/word, 52 words/row.

#define CIN    1536
#define B_DIM  512
#define COUT   512
#define WORDS3 52   // ceil(512 groups / 10 per word); word 51 holds 2 groups
#define WSTRIDE 54  // LDS row stride in uint2 (= 27 uint4); 108 dwords % 32 = 12

// ---------------- pack kernel ----------------
// 256 blocks x 256 threads. Blocks 0..127 pack x (4 rows each), 128..255 pack
// w. Coalesced float4 staging into LDS, then 1 thread per packed word.
__global__ __launch_bounds__(256) void pack_kernel(
    const float* __restrict__ x, const float* __restrict__ w,
    uint2* __restrict__ px, uint2* __restrict__ pw) {
  __shared__ float buf[4 * CIN];
  int bid = blockIdx.x;
  const float* src;
  uint2* dst;
  int row0;
  if (bid < 128) { src = x;  dst = px; row0 = bid * 4; }
  else           { src = w;  dst = pw; row0 = (bid - 128) * 4; }

  const float4* s4 = (const float4*)(src + (size_t)row0 * CIN);
  float4* b4 = (float4*)buf;
  #pragma unroll
  for (int i = threadIdx.x; i < 4 * CIN / 4; i += 256) b4[i] = s4[i];
  __syncthreads();

  int r  = threadIdx.x >> 6;   // 0..3 row within block
  int wd = threadIdx.x & 63;   // 0..63; only 0..51 active
  if (wd < WORDS3) {
    const float* rowp = buf + r * CIN + wd * 30;
    int nmax = CIN - wd * 30;  // 30 for wd<51, 6 for wd==51
    unsigned P = 0, N = 0;
    #pragma unroll
    for (int k = 0; k < 30; k++) {
      if (k < nmax) {
        float v = rowp[k];
        P |= (v > 0.0f ? 1u : 0u) << k;
        N |= (v < 0.0f ? 1u : 0u) << k;
      }
    }
    dst[(size_t)(row0 + r) * WORDS3 + wd] = make_uint2(P, N);
  }
}

// ---------------- main kernel ----------------
__device__ __forceinline__ void maj3w(unsigned xp, unsigned xn,
                                      unsigned wp, unsigned wn,
                                      int& gt, int& ge) {
  const unsigned M1 = 0x09249249u;  // bit0 of each 3-bit field (10 fields)
  const unsigned M4 = 0x24924924u;  // bit2 of each field
  unsigned pos = (xp & wp) | (xn & wn);   // product == +1 per element
  unsigned neg = (xp & wn) | (xn & wp);   // product == -1
  unsigned cp = (pos & M1) + ((pos >> 1) & M1) + ((pos >> 2) & M1); // [0,3]
  unsigned cn = (neg & M1) + ((neg >> 1) & M1) + ((neg >> 2) & M1);
  unsigned u = (cp | M4) - cn;  // field = cp-cn+4 in [1,7]; bit2 <=> cp>=cn
  unsigned t = u - M1;          // field = cp-cn+3 in [0,6]; bit2 <=> cp>cn
  gt += __popc(t & M4);
  ge += __popc(u & M4);
}

// 16x16 tile, 256 threads, 1 output/thread. grid = (32,32) = 1024 blocks
// -> 4 blocks/CU, 16 waves/CU. LDS = 2*16*54*8 = 13.8 KB.
// VGPR budget: 13 uint4 x-frag (52) + w prefetch (8) + accs/addr (~25) -> <128
// so occupancy stays 4 waves/SIMD.
__global__ __launch_bounds__(256) void maj3_kernel(
    const uint2* __restrict__ px, const uint2* __restrict__ pw,
    float* __restrict__ out) {
  __shared__ __align__(16) uint2 sx[16][WSTRIDE];
  __shared__ __align__(16) uint2 sw[16][WSTRIDE];

  const int b0 = blockIdx.y * 16;
  const int c0 = blockIdx.x * 16;
  const int tid = threadIdx.x;

  // Packed rows are dense in global: 16*26 contiguous uint4 per matrix.
  // Scatter into stride-27(uint4) LDS rows.
  const uint4* gx = (const uint4*)(px + (size_t)b0 * WORDS3);
  const uint4* gw = (const uint4*)(pw + (size_t)c0 * WORDS3);
  uint4* lx = (uint4*)sx;  // row stride 27 uint4
  uint4* lw = (uint4*)sw;
  #pragma unroll
  for (int i = tid; i < 16 * 26; i += 256) {
    int r = i / 26, wd = i - r * 26;
    lx[r * 27 + wd] = gx[i];
    lw[r * 27 + wd] = gw[i];
  }
  __syncthreads();

  const int tx = tid & 15;   // c within tile
  const int ty = tid >> 4;   // b within tile

  const uint4* xr = (const uint4*)&sx[ty][0];
  const uint4* wr = (const uint4*)&sw[tx][0];

  int gt0 = 0, ge0 = 0, gt1 = 0, ge1 = 0;
  uint4 xa[13];
  uint4 w0, w1;

  // ---- first half: x words 0..25 (13 uint4), resident in registers ----
  #pragma unroll
  for (int i = 0; i < 13; i++) xa[i] = xr[i];   // 13 independent ds_read_b128
  w0 = wr[0];
  w1 = wr[1];
  #pragma unroll
  for (int i = 0; i < 13; i++) {
    uint4 wb = w0;
    w0 = w1;
    w1 = wr[(i + 2 < 26) ? (i + 2) : 0];        // prefetch 2 ahead (valid addr)
    maj3w(xa[i].x, xa[i].y, wb.x, wb.y, gt0, ge0);
    maj3w(xa[i].z, xa[i].w, wb.z, wb.w, gt1, ge1);
  }

  // ---- second half: x words 26..51 ----
  #pragma unroll
  for (int i = 0; i < 13; i++) xa[i] = xr[13 + i];
  #pragma unroll
  for (int i = 13; i < 26; i++) {
    uint4 wb = w0;
    w0 = w1;
    w1 = wr[(i + 2 < 26) ? (i + 2) : 0];
    maj3w(xa[i - 13].x, xa[i - 13].y, wb.x, wb.y, gt0, ge0);
    maj3w(xa[i - 13].z, xa[i - 13].w, wb.z, wb.w, gt1, ge1);
  }

  // 520 fields counted (512 real + 8 zero-padded; each pad field yields
  // gt=0, ge=1 and cancels in the formula). sum(sign) = gt + ge - 520.
  out[(size_t)(b0 + ty) * COUT + (c0 + tx)] =
      2.25f * (float)(gt0 + ge0 + gt1 + ge1 - 520);
}

extern "C" void kernel_launch(void* const* d_in, const int* in_sizes, int n_in,
                              void* d_out, int out_size, void* d_ws, size_t ws_size,
                              hipStream_t stream) {
  const float* x = (const float*)d_in[0];   // [512, 1536]
  const float* w = (const float*)d_in[1];   // [512, 1536]
  float* out = (float*)d_out;               // [512, 512]

  uint2* px = (uint2*)d_ws;                  // [512][52] (208 KB)
  uint2* pw = px + (size_t)B_DIM * WORDS3;   // [512][52]

  pack_kernel<<<256, 256, 0, stream>>>(x, w, px, pw);

  dim3 grid(COUT / 16, B_DIM / 16);
  maj3_kernel<<<grid, 256, 0, stream>>>(px, pw, out);
}

// Round 6
// 69.729 us; speedup vs baseline: 1.4578x; 1.0022x over previous
//
#include <hip/hip_runtime.h>
#include <hip/hip_bf16.h>
#include <stdint.h>

// Maj3FC: out[b,c] = 2.25 * sum_g sign( sum_{k<3} sign(x[b,3g+k])*sign(w[c,3g+k]) )
// B=512, C_IN=1536, C_OUT=512, G=512 groups of 3. Exact integer math -> absmax 0.
//
// R6: occupancy push. maj3 was ~13us steady at 16 waves/CU, latency-bound
// (pipe floor ~5us). Now: 16x8 tile, 2048 blocks -> 8 blocks/CU -> 32
// waves/CU (100%). 256 threads / 128 outputs: split-K by 2 inside the block
// (sign-counts are additive), combine via 512B LDS. VGPR kept <= 64 (needed
// for 8 waves/SIMD) with rotating 2-deep x/w prefetch instead of R5's
// 13-register x residency. LDS 10.9 KB/block.
// Packing (R3): 3-bit fields, 10 groups/word, 52 words/row.

#define CIN    1536
#define B_DIM  512
#define COUT   512
#define WORDS3 52   // ceil(512 groups / 10 per word); word 51 holds 2 groups
#define WSTRIDE 54  // LDS row stride in uint2 (= 27 uint4); 108 dwords % 32 = 12

// ---------------- pack kernel ----------------
// 1024 blocks x 256 threads, 1 row per block (short latency tail).
// Coalesced float4 staging into LDS, then threads 0..51 pack one word each.
__global__ __launch_bounds__(256) void pack_kernel(
    const float* __restrict__ x, const float* __restrict__ w,
    uint2* __restrict__ px, uint2* __restrict__ pw) {
  __shared__ float buf[CIN];
  const int bid = blockIdx.x;
  const float* src;
  uint2* dst;
  if (bid < 512) { src = x + (size_t)bid * CIN;        dst = px + (size_t)bid * WORDS3; }
  else           { src = w + (size_t)(bid - 512) * CIN; dst = pw + (size_t)(bid - 512) * WORDS3; }

  const float4* s4 = (const float4*)src;
  float4* b4 = (float4*)buf;
  #pragma unroll
  for (int i = threadIdx.x; i < CIN / 4; i += 256) b4[i] = s4[i];
  __syncthreads();

  const int wd = threadIdx.x;
  if (wd < WORDS3) {
    const float* rowp = buf + wd * 30;
    int nmax = CIN - wd * 30;  // 30 for wd<51, 6 for wd==51
    unsigned P = 0, N = 0;
    #pragma unroll
    for (int k = 0; k < 30; k++) {
      if (k < nmax) {
        float v = rowp[k];
        P |= (v > 0.0f ? 1u : 0u) << k;
        N |= (v < 0.0f ? 1u : 0u) << k;
      }
    }
    dst[wd] = make_uint2(P, N);
  }
}

// ---------------- main kernel ----------------
__device__ __forceinline__ void maj3w(unsigned xp, unsigned xn,
                                      unsigned wp, unsigned wn,
                                      int& gt, int& ge) {
  const unsigned M1 = 0x09249249u;  // bit0 of each 3-bit field (10 fields)
  const unsigned M4 = 0x24924924u;  // bit2 of each field
  unsigned pos = (xp & wp) | (xn & wn);   // product == +1 per element
  unsigned neg = (xp & wn) | (xn & wp);   // product == -1
  unsigned cp = (pos & M1) + ((pos >> 1) & M1) + ((pos >> 2) & M1); // [0,3]
  unsigned cn = (neg & M1) + ((neg >> 1) & M1) + ((neg >> 2) & M1);
  unsigned u = (cp | M4) - cn;  // field = cp-cn+4 in [1,7]; bit2 <=> cp>=cn
  unsigned t = u - M1;          // field = cp-cn+3 in [0,6]; bit2 <=> cp>cn
  gt += __popc(t & M4);
  ge += __popc(u & M4);
}

// 16(b) x 8(c) tile, 256 threads, 128 outputs, split-K by 2.
// grid = (64, 32) = 2048 blocks -> 8 blocks/CU -> 32 waves/CU.
// LDS = (16+8)*54*8 + 128*4 = 10.9 KB.
__global__ __launch_bounds__(256) void maj3_kernel(
    const uint2* __restrict__ px, const uint2* __restrict__ pw,
    float* __restrict__ out) {
  __shared__ __align__(16) uint2 sx[16][WSTRIDE];
  __shared__ __align__(16) uint2 sw[8][WSTRIDE];
  __shared__ int comb[128];

  const int b0 = blockIdx.y * 16;
  const int c0 = blockIdx.x * 8;
  const int tid = threadIdx.x;

  // Packed rows are dense in global: x block = 16*26 contiguous uint4,
  // w block = 8*26. Scatter into stride-27(uint4) LDS rows.
  const uint4* gx = (const uint4*)(px + (size_t)b0 * WORDS3);
  const uint4* gw = (const uint4*)(pw + (size_t)c0 * WORDS3);
  uint4* lx = (uint4*)sx;  // row stride 27 uint4
  uint4* lw = (uint4*)sw;
  #pragma unroll
  for (int i = tid; i < 16 * 26; i += 256) {
    int r = i / 26, wd = i - r * 26;
    lx[r * 27 + wd] = gx[i];
  }
  if (tid < 8 * 26) {
    int r = tid / 26, wd = tid - r * 26;
    lw[r * 27 + wd] = gw[tid];
  }
  __syncthreads();

  const int o  = tid & 127;   // output index within tile
  const int tx = o & 7;       // c within tile
  const int ty = o >> 3;      // b within tile
  const int h  = tid >> 7;    // K-half: words [13h, 13h+13) in uint4 units

  const uint4* xr = (const uint4*)&sx[ty][0];
  const uint4* wr = (const uint4*)&sw[tx][0];
  const int hb = h * 13;

  int gt0 = 0, ge0 = 0, gt1 = 0, ge1 = 0;

  // rotating 2-deep prefetch for both operands (all addresses valid)
  uint4 x0 = xr[hb],     w0 = wr[hb];
  uint4 x1 = xr[hb + 1], w1 = wr[hb + 1];
  #pragma unroll
  for (int i = 0; i < 13; i++) {
    uint4 xa = x0, wb = w0;
    x0 = x1; w0 = w1;
    int nx = (i + 2 < 13) ? (hb + i + 2) : hb;
    x1 = xr[nx]; w1 = wr[nx];
    maj3w(xa.x, xa.y, wb.x, wb.y, gt0, ge0);
    maj3w(xa.z, xa.w, wb.z, wb.w, gt1, ge1);
  }

  int partial = gt0 + ge0 + gt1 + ge1;
  if (h == 1) comb[o] = partial;
  __syncthreads();
  if (h == 0) {
    // 520 fields total (512 real + 8 zero-pads; pads contribute ge=1 each
    // and cancel). sum(sign) = gt + ge - 520.
    int total = partial + comb[o];
    out[(size_t)(b0 + ty) * COUT + (c0 + tx)] = 2.25f * (float)(total - 520);
  }
}

extern "C" void kernel_launch(void* const* d_in, const int* in_sizes, int n_in,
                              void* d_out, int out_size, void* d_ws, size_t ws_size,
                              hipStream_t stream) {
  const float* x = (const float*)d_in[0];   // [512, 1536]
  const float* w = (const float*)d_in[1];   // [512, 1536]
  float* out = (float*)d_out;               // [512, 512]

  uint2* px = (uint2*)d_ws;                  // [512][52] (208 KB)
  uint2* pw = px + (size_t)B_DIM * WORDS3;   // [512][52]

  pack_kernel<<<1024, 256, 0, stream>>>(x, w, px, pw);

  dim3 grid(COUT / 8, B_DIM / 16);
  maj3_kernel<<<grid, 256, 0, stream>>>(px, pw, out);
}